// Round 3
// baseline (1062.522 us; speedup 1.0000x reference)
//
#include <hip/hip_runtime.h>

#define D 128
#define CHUNK 512

using short8 = __attribute__((ext_vector_type(8))) short;
using f32x4  = __attribute__((ext_vector_type(4))) float;
using f32x2  = __attribute__((ext_vector_type(2))) float;
using u32x2  = __attribute__((ext_vector_type(2))) unsigned;

__device__ __forceinline__ unsigned short f2bf(float f){
  unsigned u = __builtin_bit_cast(unsigned, f);
  u += 0x7fffu + ((u >> 16) & 1u);           // round-to-nearest-even
  return (unsigned short)(u >> 16);
}
__device__ __forceinline__ float bflo2f(unsigned v){
  return __builtin_bit_cast(float, v << 16);
}
__device__ __forceinline__ float bfhi2f(unsigned v){
  return __builtin_bit_cast(float, v & 0xffff0000u);
}

// ---------------- degree ----------------
__global__ void k_deg(const int* __restrict__ dst, int* __restrict__ deg, int E){
  int e = blockIdx.x * 256 + threadIdx.x;
  if (e < E) atomicAdd(&deg[dst[e]], 1);
}

// ---------------- scan (3-stage) ----------------
__global__ void k_chunksum(const int* __restrict__ deg, int* __restrict__ csum, int n){
  __shared__ int s[256];
  int tid = threadIdx.x;
  int n0 = blockIdx.x * CHUNK + tid * 2;
  int v = 0;
  if (n0     < n) v += deg[n0];
  if (n0 + 1 < n) v += deg[n0 + 1];
  s[tid] = v; __syncthreads();
  for (int off = 128; off > 0; off >>= 1){
    if (tid < off) s[tid] += s[tid + off];
    __syncthreads();
  }
  if (tid == 0) csum[blockIdx.x] = s[0];
}

__global__ void k_scanchunks(int* __restrict__ csum, int nchunks){
  __shared__ int s[256];
  int tid = threadIdx.x;
  int v = (tid < nchunks) ? csum[tid] : 0;
  s[tid] = v; __syncthreads();
  for (int off = 1; off < 256; off <<= 1){
    int t = (tid >= off) ? s[tid - off] : 0;
    __syncthreads();
    s[tid] += t;
    __syncthreads();
  }
  if (tid < nchunks) csum[tid] = s[tid] - v;   // exclusive
}

__global__ void k_offsets(const int* __restrict__ deg, const int* __restrict__ csum,
                          int* __restrict__ offs, float* __restrict__ inv, int n){
  __shared__ int s[256];
  int tid = threadIdx.x;
  int n0 = blockIdx.x * CHUNK + tid * 2;
  int d0 = (n0     < n) ? deg[n0]     : 0;
  int d1 = (n0 + 1 < n) ? deg[n0 + 1] : 0;
  int pair = d0 + d1;
  s[tid] = pair; __syncthreads();
  for (int off = 1; off < 256; off <<= 1){
    int t = (tid >= off) ? s[tid - off] : 0;
    __syncthreads();
    s[tid] += t;
    __syncthreads();
  }
  int excl = s[tid] - pair + csum[blockIdx.x];
  if (n0     <= n) offs[n0]     = excl;
  if (n0 + 1 <= n) offs[n0 + 1] = excl + d0;
  if (n0     < n) inv[n0]     = rsqrtf((float)(d0 + 1));
  if (n0 + 1 < n) inv[n0 + 1] = rsqrtf((float)(d1 + 1));
}

// ---------------- CSR fill (packed src+weight) ----------------
__global__ void k_csrfill(const int* __restrict__ src, const int* __restrict__ dst,
                          const int* __restrict__ offs, int* __restrict__ cursor,
                          const float* __restrict__ inv, int2* __restrict__ ce, int E){
  int e = blockIdx.x * 256 + threadIdx.x;
  if (e >= E) return;
  int s = src[e], d = dst[e];
  int pos = offs[d] + atomicAdd(&cursor[d], 1);
  int2 v;
  v.x = s;
  v.y = __builtin_bit_cast(int, inv[s] * inv[d]);
  ce[pos] = v;
}

// ---------------- GEMM: hw(bf16) = act(hin) @ W ----------------
#define WSTRIDE 136
__global__ __launch_bounds__(512)
void k_gemm(const float* __restrict__ hin, const float* __restrict__ W,
            const float* __restrict__ scale, const float* __restrict__ shift,
            int do_norm, unsigned short* __restrict__ hw, int nrows){
  __shared__ unsigned short Wt[128 * WSTRIDE];  // transposed, padded
  int tid = threadIdx.x;
  for (int i = tid; i < 128 * 128; i += 512){
    int k = i >> 7, c = i & 127;
    Wt[c * WSTRIDE + k] = f2bf(W[i]);
  }
  __syncthreads();

  int wave = tid >> 6, lane = tid & 63;
  int r0 = blockIdx.x * 128 + wave * 16;
  int row = r0 + (lane & 15);
  int kg = lane >> 4;
  int rowc = row < nrows ? row : nrows - 1;
  const float* hrow = hin + (long)rowc * D;

  short8 a[4];
#pragma unroll
  for (int kt = 0; kt < 4; ++kt){
    int k0 = kt * 32 + kg * 8;
    f32x4 v0 = *(const f32x4*)(hrow + k0);
    f32x4 v1 = *(const f32x4*)(hrow + k0 + 4);
    float v[8] = {v0[0], v0[1], v0[2], v0[3], v1[0], v1[1], v1[2], v1[3]};
    if (do_norm){
#pragma unroll
      for (int j = 0; j < 8; ++j)
        v[j] = fmaxf(0.f, v[j] * scale[k0 + j] + shift[k0 + j]);
    }
    short8 t;
#pragma unroll
    for (int j = 0; j < 8; ++j) t[j] = (short)f2bf(v[j]);
    a[kt] = t;
  }

  f32x4 acc[8] = {};
#pragma unroll
  for (int ct = 0; ct < 8; ++ct){
    int col = ct * 16 + (lane & 15);
    const unsigned short* bp = &Wt[col * WSTRIDE + kg * 8];
#pragma unroll
    for (int kt = 0; kt < 4; ++kt){
      short8 b = *(const short8*)(bp + kt * 32);
      acc[ct] = __builtin_amdgcn_mfma_f32_16x16x32_bf16(a[kt], b, acc[ct], 0, 0, 0);
    }
  }

  int colbase = lane & 15;
  int rowo = r0 + kg * 4;
#pragma unroll
  for (int ct = 0; ct < 8; ++ct){
    int col = ct * 16 + colbase;
#pragma unroll
    for (int r = 0; r < 4; ++r){
      int rr = rowo + r;
      if (rr < nrows) hw[(long)rr * D + col] = f2bf(acc[ct][r]);
    }
  }
}

// ---------------- aggregate + BN partial stats ----------------
// 2 edges per gather instruction (lane halves by edge parity, uint2 = 4 cols
// per lane), packed ce loads, fully-predicated unrolled tail, shfl fold.
__global__ __launch_bounds__(256)
void k_agg(const unsigned short* __restrict__ hw, const float* __restrict__ inv,
           const int* __restrict__ offs, const int2* __restrict__ ce,
           const float* __restrict__ bias,
           float* __restrict__ agg, float* __restrict__ stats, int n){
  int tid = threadIdx.x, lane = tid & 63, wv = tid >> 6;
  int g = lane >> 5, li = lane & 31;
  int gw = blockIdx.x * 4 + wv;
  int nwaves = gridDim.x * 4;
  int per = (n + nwaves - 1) / nwaves;
  int n0 = gw * per, n1 = min(n0 + per, n);
  int c0 = li * 4;
  f32x4 bb = *(const f32x4*)(bias + c0);
  float s0=0,s1=0,s2=0,s3=0,q0=0,q1=0,q2=0,q3=0;

  for (int nd = n0; nd < n1; ++nd){
    float iv = inv[nd];
    float self = iv * iv;
    float acc[4][4] = {{0,0,0,0},{0,0,0,0},{0,0,0,0},{0,0,0,0}};
    int e = offs[nd], ee = offs[nd + 1];
    for (; e + 8 <= ee; e += 8){
#pragma unroll
      for (int p = 0; p < 4; ++p){
        int2 c = ce[e + 2 * p + g];
        float w = __builtin_bit_cast(float, c.y);
        u32x2 v = *(const u32x2*)(hw + (long)c.x * D + c0);
        acc[p][0] += bflo2f(v[0]) * w;
        acc[p][1] += bfhi2f(v[0]) * w;
        acc[p][2] += bflo2f(v[1]) * w;
        acc[p][3] += bfhi2f(v[1]) * w;
      }
    }
    if (e < ee){
#pragma unroll
      for (int p = 0; p < 4; ++p){
        int idx = e + 2 * p + g;
        bool ok = idx < ee;
        int2 c = ce[ok ? idx : ee - 1];
        float w = ok ? __builtin_bit_cast(float, c.y) : 0.f;
        u32x2 v = *(const u32x2*)(hw + (long)c.x * D + c0);
        acc[p][0] += bflo2f(v[0]) * w;
        acc[p][1] += bfhi2f(v[0]) * w;
        acc[p][2] += bflo2f(v[1]) * w;
        acc[p][3] += bfhi2f(v[1]) * w;
      }
    }
    float a0 = (acc[0][0] + acc[1][0]) + (acc[2][0] + acc[3][0]);
    float a1 = (acc[0][1] + acc[1][1]) + (acc[2][1] + acc[3][1]);
    float a2 = (acc[0][2] + acc[1][2]) + (acc[2][2] + acc[3][2]);
    float a3 = (acc[0][3] + acc[1][3]) + (acc[2][3] + acc[3][3]);
    a0 += __shfl_xor(a0, 32, 64);
    a1 += __shfl_xor(a1, 32, 64);
    a2 += __shfl_xor(a2, 32, 64);
    a3 += __shfl_xor(a3, 32, 64);
    if (g == 0){
      u32x2 sv = *(const u32x2*)(hw + (long)nd * D + c0);
      a0 += bflo2f(sv[0]) * self + bb[0];
      a1 += bfhi2f(sv[0]) * self + bb[1];
      a2 += bflo2f(sv[1]) * self + bb[2];
      a3 += bfhi2f(sv[1]) * self + bb[3];
      f32x4 r; r[0] = a0; r[1] = a1; r[2] = a2; r[3] = a3;
      __builtin_nontemporal_store(r, (f32x4*)(agg + (long)nd * D + c0));
      s0 += a0; s1 += a1; s2 += a2; s3 += a3;
      q0 += a0 * a0; q1 += a1 * a1; q2 += a2 * a2; q3 += a3 * a3;
    }
  }

  __shared__ float red[4][32][8];
  if (g == 0){
    red[wv][li][0] = s0; red[wv][li][1] = s1;
    red[wv][li][2] = s2; red[wv][li][3] = s3;
    red[wv][li][4] = q0; red[wv][li][5] = q1;
    red[wv][li][6] = q2; red[wv][li][7] = q3;
  }
  __syncthreads();
  if (tid < 32){
    float t[8] = {0,0,0,0,0,0,0,0};
#pragma unroll
    for (int w = 0; w < 4; ++w)
#pragma unroll
      for (int j = 0; j < 8; ++j) t[j] += red[w][tid][j];
#pragma unroll
    for (int j = 0; j < 4; ++j){
      atomicAdd(&stats[tid * 4 + j],       t[j]);
      atomicAdd(&stats[128 + tid * 4 + j], t[4 + j]);
    }
  }
}

// ---------------- BN finalize ----------------
__global__ void k_bn(const float* __restrict__ stats, const float* __restrict__ gamma,
                     const float* __restrict__ beta, float* __restrict__ scale,
                     float* __restrict__ shift, float invn){
  int c = threadIdx.x;
  float mean = stats[c] * invn;
  float var = stats[128 + c] * invn - mean * mean;
  float isd = rsqrtf(var + 1e-5f);
  float sc = gamma[c] * isd;
  scale[c] = sc;
  shift[c] = beta[c] - mean * sc;
}

// ---------------- pool (fused BN+ReLU of last layer) ----------------
__global__ __launch_bounds__(256)
void k_pool(const float* __restrict__ agg, const float* __restrict__ scale,
            const float* __restrict__ shift, const int* __restrict__ batch,
            float* __restrict__ out, int n){
  int tid = threadIdx.x, lane = tid & 63, wv = tid >> 6;
  int gw = blockIdx.x * 4 + wv;
  int n0 = gw * 64;
  if (n0 >= n) return;
  int n1 = min(n0 + 64, n);
  int c0 = lane * 2;
  float sc0 = scale[c0], sc1 = scale[c0 + 1];
  float sh0 = shift[c0], sh1 = shift[c0 + 1];
  int g = batch[n0];
  float a0 = 0, a1 = 0;
  for (int nd = n0; nd < n1; ++nd){
    int gn = batch[nd];
    if (gn != g){
      atomicAdd(&out[(long)g * D + c0],     a0);
      atomicAdd(&out[(long)g * D + c0 + 1], a1);
      a0 = 0; a1 = 0; g = gn;
    }
    f32x2 v = *(const f32x2*)(agg + (long)nd * D + c0);
    a0 += fmaxf(0.f, v[0] * sc0 + sh0);
    a1 += fmaxf(0.f, v[1] * sc1 + sh1);
  }
  atomicAdd(&out[(long)g * D + c0],     a0);
  atomicAdd(&out[(long)g * D + c0 + 1], a1);
}

extern "C" void kernel_launch(void* const* d_in, const int* in_sizes, int n_in,
                              void* d_out, int out_size, void* d_ws, size_t ws_size,
                              hipStream_t stream){
  const float* x      = (const float*)d_in[0];
  const int*   ei     = (const int*)d_in[1];
  const int*   batch  = (const int*)d_in[2];
  const float* Ws     = (const float*)d_in[3];
  const float* bs     = (const float*)d_in[4];
  const float* gammas = (const float*)d_in[5];
  const float* betas  = (const float*)d_in[6];

  const int E_ = in_sizes[1] / 2;
  const int N_ = in_sizes[2];
  const int* src = ei;
  const int* dst = ei + E_;

  char* p = (char*)d_ws;
  auto alloc = [&](size_t bytes) -> void* {
    void* r = (void*)p;
    p += (bytes + 255) & ~(size_t)255;
    return r;
  };
  float*          bufA   = (float*)         alloc((size_t)N_ * D * 4);
  unsigned short* hw     = (unsigned short*)alloc((size_t)N_ * D * 2);
  int*            deg    = (int*)           alloc((size_t)N_ * 4);
  float*          inv    = (float*)         alloc((size_t)N_ * 4);
  int*            offs   = (int*)           alloc((size_t)(N_ + 1) * 4);
  int*            cursor = (int*)           alloc((size_t)N_ * 4);
  int2*           ce     = (int2*)          alloc((size_t)E_ * 8);
  float*          stats  = (float*)         alloc(3 * 256 * 4);
  float*          scales = (float*)         alloc(3 * 128 * 4);
  float*          shifts = (float*)         alloc(3 * 128 * 4);
  int*            csum   = (int*)           alloc(256 * 4);

  hipMemsetAsync(deg,    0, (size_t)N_ * 4, stream);
  hipMemsetAsync(cursor, 0, (size_t)N_ * 4, stream);
  hipMemsetAsync(stats,  0, 3 * 256 * 4, stream);
  hipMemsetAsync(d_out,  0, (size_t)out_size * 4, stream);

  int nchunks = (N_ + CHUNK - 1) / CHUNK;
  k_deg       <<<(E_ + 255) / 256, 256, 0, stream>>>(dst, deg, E_);
  k_chunksum  <<<nchunks, 256, 0, stream>>>(deg, csum, N_);
  k_scanchunks<<<1, 256, 0, stream>>>(csum, nchunks);
  k_offsets   <<<nchunks, 256, 0, stream>>>(deg, csum, offs, inv, N_);
  k_csrfill   <<<(E_ + 255) / 256, 256, 0, stream>>>(src, dst, offs, cursor, inv, ce, E_);

  int gemm_blocks = (N_ + 127) / 128;
  for (int l = 0; l < 3; ++l){
    const float* hin = (l == 0) ? x : bufA;
    const float* sc  = (l == 0) ? nullptr : scales + (l - 1) * 128;
    const float* sh  = (l == 0) ? nullptr : shifts + (l - 1) * 128;
    k_gemm<<<gemm_blocks, 512, 0, stream>>>(hin, Ws + (size_t)l * D * D, sc, sh,
                                            (l == 0) ? 0 : 1, hw, N_);
    k_agg<<<2048, 256, 0, stream>>>(hw, inv, offs, ce, bs + (size_t)l * D,
                                    bufA, stats + (size_t)l * 256, N_);
    k_bn<<<1, 128, 0, stream>>>(stats + (size_t)l * 256, gammas + (size_t)l * D,
                                betas + (size_t)l * D, scales + (size_t)l * 128,
                                shifts + (size_t)l * 128, 1.0f / (float)N_);
  }
  k_pool<<<(N_ + 255) / 256, 256, 0, stream>>>(bufA, scales + 2 * 128, shifts + 2 * 128,
                                               batch, (float*)d_out, N_);
}

// Round 4
// 834.385 us; speedup vs baseline: 1.2734x; 1.2734x over previous
//
#include <hip/hip_runtime.h>

#define D 128
#define CHUNK 512

using short8 = __attribute__((ext_vector_type(8))) short;
using f32x4  = __attribute__((ext_vector_type(4))) float;
using f32x2  = __attribute__((ext_vector_type(2))) float;

__device__ __forceinline__ unsigned short f2bf(float f){
  unsigned u = __builtin_bit_cast(unsigned, f);
  u += 0x7fffu + ((u >> 16) & 1u);           // round-to-nearest-even
  return (unsigned short)(u >> 16);
}
__device__ __forceinline__ float bflo2f(unsigned v){
  return __builtin_bit_cast(float, v << 16);
}
__device__ __forceinline__ float bfhi2f(unsigned v){
  return __builtin_bit_cast(float, v & 0xffff0000u);
}

// ---------------- degree ----------------
__global__ void k_deg(const int* __restrict__ dst, int* __restrict__ deg, int E){
  int e = blockIdx.x * 256 + threadIdx.x;
  if (e < E) atomicAdd(&deg[dst[e]], 1);
}

// ---------------- scan (3-stage) ----------------
__global__ void k_chunksum(const int* __restrict__ deg, int* __restrict__ csum, int n){
  __shared__ int s[256];
  int tid = threadIdx.x;
  int n0 = blockIdx.x * CHUNK + tid * 2;
  int v = 0;
  if (n0     < n) v += deg[n0];
  if (n0 + 1 < n) v += deg[n0 + 1];
  s[tid] = v; __syncthreads();
  for (int off = 128; off > 0; off >>= 1){
    if (tid < off) s[tid] += s[tid + off];
    __syncthreads();
  }
  if (tid == 0) csum[blockIdx.x] = s[0];
}

__global__ void k_scanchunks(int* __restrict__ csum, int nchunks){
  __shared__ int s[256];
  int tid = threadIdx.x;
  int v = (tid < nchunks) ? csum[tid] : 0;
  s[tid] = v; __syncthreads();
  for (int off = 1; off < 256; off <<= 1){
    int t = (tid >= off) ? s[tid - off] : 0;
    __syncthreads();
    s[tid] += t;
    __syncthreads();
  }
  if (tid < nchunks) csum[tid] = s[tid] - v;   // exclusive
}

__global__ void k_offsets(const int* __restrict__ deg, const int* __restrict__ csum,
                          int* __restrict__ offs, float* __restrict__ inv, int n){
  __shared__ int s[256];
  int tid = threadIdx.x;
  int n0 = blockIdx.x * CHUNK + tid * 2;
  int d0 = (n0     < n) ? deg[n0]     : 0;
  int d1 = (n0 + 1 < n) ? deg[n0 + 1] : 0;
  int pair = d0 + d1;
  s[tid] = pair; __syncthreads();
  for (int off = 1; off < 256; off <<= 1){
    int t = (tid >= off) ? s[tid - off] : 0;
    __syncthreads();
    s[tid] += t;
    __syncthreads();
  }
  int excl = s[tid] - pair + csum[blockIdx.x];
  if (n0     <= n) offs[n0]     = excl;
  if (n0 + 1 <= n) offs[n0 + 1] = excl + d0;
  if (n0     < n) inv[n0]     = rsqrtf((float)(d0 + 1));
  if (n0 + 1 < n) inv[n0 + 1] = rsqrtf((float)(d1 + 1));
}

// ---------------- CSR fill ----------------
__global__ void k_csrfill(const int* __restrict__ src, const int* __restrict__ dst,
                          const int* __restrict__ offs, int* __restrict__ cursor,
                          const float* __restrict__ inv, int* __restrict__ csrc,
                          float* __restrict__ cw, int E){
  int e = blockIdx.x * 256 + threadIdx.x;
  if (e >= E) return;
  int s = src[e], d = dst[e];
  int pos = offs[d] + atomicAdd(&cursor[d], 1);
  csrc[pos] = s;
  cw[pos] = inv[s] * inv[d];
}

// ---------------- GEMM: hw(bf16) = act(hin) @ W ----------------
#define WSTRIDE 136
__global__ __launch_bounds__(512)
void k_gemm(const float* __restrict__ hin, const float* __restrict__ W,
            const float* __restrict__ scale, const float* __restrict__ shift,
            int do_norm, unsigned short* __restrict__ hw, int nrows){
  __shared__ unsigned short Wt[128 * WSTRIDE];  // transposed, padded
  int tid = threadIdx.x;
  for (int i = tid; i < 128 * 128; i += 512){
    int k = i >> 7, c = i & 127;
    Wt[c * WSTRIDE + k] = f2bf(W[i]);
  }
  __syncthreads();

  int wave = tid >> 6, lane = tid & 63;
  int r0 = blockIdx.x * 128 + wave * 16;
  int row = r0 + (lane & 15);
  int kg = lane >> 4;
  int rowc = row < nrows ? row : nrows - 1;
  const float* hrow = hin + (long)rowc * D;

  short8 a[4];
#pragma unroll
  for (int kt = 0; kt < 4; ++kt){
    int k0 = kt * 32 + kg * 8;
    f32x4 v0 = *(const f32x4*)(hrow + k0);
    f32x4 v1 = *(const f32x4*)(hrow + k0 + 4);
    float v[8] = {v0[0], v0[1], v0[2], v0[3], v1[0], v1[1], v1[2], v1[3]};
    if (do_norm){
#pragma unroll
      for (int j = 0; j < 8; ++j)
        v[j] = fmaxf(0.f, v[j] * scale[k0 + j] + shift[k0 + j]);
    }
    short8 t;
#pragma unroll
    for (int j = 0; j < 8; ++j) t[j] = (short)f2bf(v[j]);
    a[kt] = t;
  }

  f32x4 acc[8] = {};
#pragma unroll
  for (int ct = 0; ct < 8; ++ct){
    int col = ct * 16 + (lane & 15);
    const unsigned short* bp = &Wt[col * WSTRIDE + kg * 8];
#pragma unroll
    for (int kt = 0; kt < 4; ++kt){
      short8 b = *(const short8*)(bp + kt * 32);
      acc[ct] = __builtin_amdgcn_mfma_f32_16x16x32_bf16(a[kt], b, acc[ct], 0, 0, 0);
    }
  }

  int colbase = lane & 15;
  int rowo = r0 + kg * 4;
#pragma unroll
  for (int ct = 0; ct < 8; ++ct){
    int col = ct * 16 + colbase;
#pragma unroll
    for (int r = 0; r < 4; ++r){
      int rr = rowo + r;
      if (rr < nrows) hw[(long)rr * D + col] = f2bf(acc[ct][r]);
    }
  }
}

// ---------------- aggregate + BN partial stats ----------------
// R2 structure (uniform scalar csrc/cw loads, full-wave 256B row gathers),
// widened to 8 independent gathers in flight + 8-wide predicated tail.
__global__ __launch_bounds__(256)
void k_agg(const unsigned short* __restrict__ hw, const float* __restrict__ inv,
           const int* __restrict__ offs, const int* __restrict__ csrc,
           const float* __restrict__ cw, const float* __restrict__ bias,
           float* __restrict__ agg, float* __restrict__ stats, int n){
  int tid = threadIdx.x, lane = tid & 63, wv = tid >> 6;
  int gw = blockIdx.x * 4 + wv;
  int nwaves = gridDim.x * 4;
  int per = (n + nwaves - 1) / nwaves;
  int n0 = gw * per, n1 = min(n0 + per, n);
  int c0 = lane * 2;
  float b0 = bias[c0], b1 = bias[c0 + 1];
  float s0 = 0, s1 = 0, q0 = 0, q1 = 0;

  for (int nd = n0; nd < n1; ++nd){
    float iv = inv[nd];
    float self = iv * iv;
    unsigned v = *(const unsigned*)(hw + (long)nd * D + c0);
    float a0 = bflo2f(v) * self + b0;
    float a1 = bfhi2f(v) * self + b1;
    float x0[8] = {0,0,0,0,0,0,0,0};
    float x1[8] = {0,0,0,0,0,0,0,0};
    int e = offs[nd], ee = offs[nd + 1];
    for (; e + 8 <= ee; e += 8){
#pragma unroll
      for (int p = 0; p < 8; ++p){
        int s = csrc[e + p];
        float w = cw[e + p];
        unsigned vv = *(const unsigned*)(hw + (long)s * D + c0);
        x0[p] += bflo2f(vv) * w;
        x1[p] += bfhi2f(vv) * w;
      }
    }
    if (e < ee){
      int last = ee - 1;
#pragma unroll
      for (int p = 0; p < 8; ++p){
        int idx = e + p;
        bool ok = idx < ee;
        int ic = ok ? idx : last;
        int s = csrc[ic];
        float w = ok ? cw[ic] : 0.f;
        unsigned vv = *(const unsigned*)(hw + (long)s * D + c0);
        x0[p] += bflo2f(vv) * w;
        x1[p] += bfhi2f(vv) * w;
      }
    }
    a0 += ((x0[0] + x0[1]) + (x0[2] + x0[3])) + ((x0[4] + x0[5]) + (x0[6] + x0[7]));
    a1 += ((x1[0] + x1[1]) + (x1[2] + x1[3])) + ((x1[4] + x1[5]) + (x1[6] + x1[7]));
    f32x2 rr; rr[0] = a0; rr[1] = a1;
    __builtin_nontemporal_store(rr, (f32x2*)(agg + (long)nd * D + c0));
    s0 += a0; s1 += a1; q0 += a0 * a0; q1 += a1 * a1;
  }

  __shared__ float red[4][64][4];
  red[wv][lane][0] = s0; red[wv][lane][1] = s1;
  red[wv][lane][2] = q0; red[wv][lane][3] = q1;
  __syncthreads();
  if (tid < 64){
    float t0 = 0, t1 = 0, t2 = 0, t3 = 0;
#pragma unroll
    for (int w = 0; w < 4; ++w){
      t0 += red[w][tid][0]; t1 += red[w][tid][1];
      t2 += red[w][tid][2]; t3 += red[w][tid][3];
    }
    atomicAdd(&stats[2 * tid],           t0);
    atomicAdd(&stats[2 * tid + 1],       t1);
    atomicAdd(&stats[128 + 2 * tid],     t2);
    atomicAdd(&stats[128 + 2 * tid + 1], t3);
  }
}

// ---------------- BN finalize ----------------
__global__ void k_bn(const float* __restrict__ stats, const float* __restrict__ gamma,
                     const float* __restrict__ beta, float* __restrict__ scale,
                     float* __restrict__ shift, float invn){
  int c = threadIdx.x;
  float mean = stats[c] * invn;
  float var = stats[128 + c] * invn - mean * mean;
  float isd = rsqrtf(var + 1e-5f);
  float sc = gamma[c] * isd;
  scale[c] = sc;
  shift[c] = beta[c] - mean * sc;
}

// ---------------- pool (fused BN+ReLU of last layer) ----------------
__global__ __launch_bounds__(256)
void k_pool(const float* __restrict__ agg, const float* __restrict__ scale,
            const float* __restrict__ shift, const int* __restrict__ batch,
            float* __restrict__ out, int n){
  int tid = threadIdx.x, lane = tid & 63, wv = tid >> 6;
  int gw = blockIdx.x * 4 + wv;
  int n0 = gw * 64;
  if (n0 >= n) return;
  int n1 = min(n0 + 64, n);
  int c0 = lane * 2;
  float sc0 = scale[c0], sc1 = scale[c0 + 1];
  float sh0 = shift[c0], sh1 = shift[c0 + 1];
  int g = batch[n0];
  float a0 = 0, a1 = 0;
  for (int nd = n0; nd < n1; ++nd){
    int gn = batch[nd];
    if (gn != g){
      atomicAdd(&out[(long)g * D + c0],     a0);
      atomicAdd(&out[(long)g * D + c0 + 1], a1);
      a0 = 0; a1 = 0; g = gn;
    }
    f32x2 v = *(const f32x2*)(agg + (long)nd * D + c0);
    a0 += fmaxf(0.f, v[0] * sc0 + sh0);
    a1 += fmaxf(0.f, v[1] * sc1 + sh1);
  }
  atomicAdd(&out[(long)g * D + c0],     a0);
  atomicAdd(&out[(long)g * D + c0 + 1], a1);
}

extern "C" void kernel_launch(void* const* d_in, const int* in_sizes, int n_in,
                              void* d_out, int out_size, void* d_ws, size_t ws_size,
                              hipStream_t stream){
  const float* x      = (const float*)d_in[0];
  const int*   ei     = (const int*)d_in[1];
  const int*   batch  = (const int*)d_in[2];
  const float* Ws     = (const float*)d_in[3];
  const float* bs     = (const float*)d_in[4];
  const float* gammas = (const float*)d_in[5];
  const float* betas  = (const float*)d_in[6];

  const int E_ = in_sizes[1] / 2;
  const int N_ = in_sizes[2];
  const int* src = ei;
  const int* dst = ei + E_;

  char* p = (char*)d_ws;
  auto alloc = [&](size_t bytes) -> void* {
    void* r = (void*)p;
    p += (bytes + 255) & ~(size_t)255;
    return r;
  };
  float*          bufA   = (float*)         alloc((size_t)N_ * D * 4);
  unsigned short* hw     = (unsigned short*)alloc((size_t)N_ * D * 2);
  int*            deg    = (int*)           alloc((size_t)N_ * 4);
  float*          inv    = (float*)         alloc((size_t)N_ * 4);
  int*            offs   = (int*)           alloc((size_t)(N_ + 1) * 4);
  int*            cursor = (int*)           alloc((size_t)N_ * 4);
  int*            csrc   = (int*)           alloc((size_t)E_ * 4);
  float*          cwt    = (float*)         alloc((size_t)E_ * 4);
  float*          stats  = (float*)         alloc(3 * 256 * 4);
  float*          scales = (float*)         alloc(3 * 128 * 4);
  float*          shifts = (float*)         alloc(3 * 128 * 4);
  int*            csum   = (int*)           alloc(256 * 4);

  hipMemsetAsync(deg,    0, (size_t)N_ * 4, stream);
  hipMemsetAsync(cursor, 0, (size_t)N_ * 4, stream);
  hipMemsetAsync(stats,  0, 3 * 256 * 4, stream);
  hipMemsetAsync(d_out,  0, (size_t)out_size * 4, stream);

  int nchunks = (N_ + CHUNK - 1) / CHUNK;
  k_deg       <<<(E_ + 255) / 256, 256, 0, stream>>>(dst, deg, E_);
  k_chunksum  <<<nchunks, 256, 0, stream>>>(deg, csum, N_);
  k_scanchunks<<<1, 256, 0, stream>>>(csum, nchunks);
  k_offsets   <<<nchunks, 256, 0, stream>>>(deg, csum, offs, inv, N_);
  k_csrfill   <<<(E_ + 255) / 256, 256, 0, stream>>>(src, dst, offs, cursor, inv, csrc, cwt, E_);

  int gemm_blocks = (N_ + 127) / 128;
  for (int l = 0; l < 3; ++l){
    const float* hin = (l == 0) ? x : bufA;
    const float* sc  = (l == 0) ? nullptr : scales + (l - 1) * 128;
    const float* sh  = (l == 0) ? nullptr : shifts + (l - 1) * 128;
    k_gemm<<<gemm_blocks, 512, 0, stream>>>(hin, Ws + (size_t)l * D * D, sc, sh,
                                            (l == 0) ? 0 : 1, hw, N_);
    k_agg<<<2048, 256, 0, stream>>>(hw, inv, offs, csrc, cwt, bs + (size_t)l * D,
                                    bufA, stats + (size_t)l * 256, N_);
    k_bn<<<1, 128, 0, stream>>>(stats + (size_t)l * 256, gammas + (size_t)l * D,
                                betas + (size_t)l * D, scales + (size_t)l * 128,
                                shifts + (size_t)l * 128, 1.0f / (float)N_);
  }
  k_pool<<<(N_ + 255) / 256, 256, 0, stream>>>(bufA, scales + 2 * 128, shifts + 2 * 128,
                                               batch, (float*)d_out, N_);
}

// Round 5
// 789.538 us; speedup vs baseline: 1.3458x; 1.0568x over previous
//
#include <hip/hip_runtime.h>

#define D 128
#define CHUNK 512

using short8 = __attribute__((ext_vector_type(8))) short;
using f32x4  = __attribute__((ext_vector_type(4))) float;
using f32x2  = __attribute__((ext_vector_type(2))) float;

__device__ __forceinline__ unsigned short f2bf(float f){
  unsigned u = __builtin_bit_cast(unsigned, f);
  u += 0x7fffu + ((u >> 16) & 1u);           // round-to-nearest-even
  return (unsigned short)(u >> 16);
}
__device__ __forceinline__ float bflo2f(unsigned v){
  return __builtin_bit_cast(float, v << 16);
}
__device__ __forceinline__ float bfhi2f(unsigned v){
  return __builtin_bit_cast(float, v & 0xffff0000u);
}

// ---------------- degree ----------------
__global__ void k_deg(const int* __restrict__ dst, int* __restrict__ deg, int E){
  int e = blockIdx.x * 256 + threadIdx.x;
  if (e < E) atomicAdd(&deg[dst[e]], 1);
}

// ---------------- scan (3-stage) ----------------
__global__ void k_chunksum(const int* __restrict__ deg, int* __restrict__ csum, int n){
  __shared__ int s[256];
  int tid = threadIdx.x;
  int n0 = blockIdx.x * CHUNK + tid * 2;
  int v = 0;
  if (n0     < n) v += deg[n0];
  if (n0 + 1 < n) v += deg[n0 + 1];
  s[tid] = v; __syncthreads();
  for (int off = 128; off > 0; off >>= 1){
    if (tid < off) s[tid] += s[tid + off];
    __syncthreads();
  }
  if (tid == 0) csum[blockIdx.x] = s[0];
}

__global__ void k_scanchunks(int* __restrict__ csum, int nchunks){
  __shared__ int s[256];
  int tid = threadIdx.x;
  int v = (tid < nchunks) ? csum[tid] : 0;
  s[tid] = v; __syncthreads();
  for (int off = 1; off < 256; off <<= 1){
    int t = (tid >= off) ? s[tid - off] : 0;
    __syncthreads();
    s[tid] += t;
    __syncthreads();
  }
  if (tid < nchunks) csum[tid] = s[tid] - v;   // exclusive
}

__global__ void k_offsets(const int* __restrict__ deg, const int* __restrict__ csum,
                          int* __restrict__ offs, float* __restrict__ inv, int n){
  __shared__ int s[256];
  int tid = threadIdx.x;
  int n0 = blockIdx.x * CHUNK + tid * 2;
  int d0 = (n0     < n) ? deg[n0]     : 0;
  int d1 = (n0 + 1 < n) ? deg[n0 + 1] : 0;
  int pair = d0 + d1;
  s[tid] = pair; __syncthreads();
  for (int off = 1; off < 256; off <<= 1){
    int t = (tid >= off) ? s[tid - off] : 0;
    __syncthreads();
    s[tid] += t;
    __syncthreads();
  }
  int excl = s[tid] - pair + csum[blockIdx.x];
  if (n0     <= n) offs[n0]     = excl;
  if (n0 + 1 <= n) offs[n0 + 1] = excl + d0;
  if (n0     < n) inv[n0]     = rsqrtf((float)(d0 + 1));
  if (n0 + 1 < n) inv[n0 + 1] = rsqrtf((float)(d1 + 1));
}

// ---------------- CSR fill ----------------
__global__ void k_csrfill(const int* __restrict__ src, const int* __restrict__ dst,
                          const int* __restrict__ offs, int* __restrict__ cursor,
                          const float* __restrict__ inv, int* __restrict__ csrc,
                          float* __restrict__ cw, int E){
  int e = blockIdx.x * 256 + threadIdx.x;
  if (e >= E) return;
  int s = src[e], d = dst[e];
  int pos = offs[d] + atomicAdd(&cursor[d], 1);
  csrc[pos] = s;
  cw[pos] = inv[s] * inv[d];
}

// ---------------- GEMM: hw(bf16) = act(hin) @ W ----------------
#define WSTRIDE 136
__global__ __launch_bounds__(512)
void k_gemm(const float* __restrict__ hin, const float* __restrict__ W,
            const float* __restrict__ scale, const float* __restrict__ shift,
            int do_norm, unsigned short* __restrict__ hw, int nrows){
  __shared__ unsigned short Wt[128 * WSTRIDE];  // transposed, padded
  int tid = threadIdx.x;
  for (int i = tid; i < 128 * 128; i += 512){
    int k = i >> 7, c = i & 127;
    Wt[c * WSTRIDE + k] = f2bf(W[i]);
  }
  __syncthreads();

  int wave = tid >> 6, lane = tid & 63;
  int r0 = blockIdx.x * 128 + wave * 16;
  int row = r0 + (lane & 15);
  int kg = lane >> 4;
  int rowc = row < nrows ? row : nrows - 1;
  const float* hrow = hin + (long)rowc * D;

  short8 a[4];
#pragma unroll
  for (int kt = 0; kt < 4; ++kt){
    int k0 = kt * 32 + kg * 8;
    f32x4 v0 = *(const f32x4*)(hrow + k0);
    f32x4 v1 = *(const f32x4*)(hrow + k0 + 4);
    float v[8] = {v0[0], v0[1], v0[2], v0[3], v1[0], v1[1], v1[2], v1[3]};
    if (do_norm){
#pragma unroll
      for (int j = 0; j < 8; ++j)
        v[j] = fmaxf(0.f, v[j] * scale[k0 + j] + shift[k0 + j]);
    }
    short8 t;
#pragma unroll
    for (int j = 0; j < 8; ++j) t[j] = (short)f2bf(v[j]);
    a[kt] = t;
  }

  f32x4 acc[8] = {};
#pragma unroll
  for (int ct = 0; ct < 8; ++ct){
    int col = ct * 16 + (lane & 15);
    const unsigned short* bp = &Wt[col * WSTRIDE + kg * 8];
#pragma unroll
    for (int kt = 0; kt < 4; ++kt){
      short8 b = *(const short8*)(bp + kt * 32);
      acc[ct] = __builtin_amdgcn_mfma_f32_16x16x32_bf16(a[kt], b, acc[ct], 0, 0, 0);
    }
  }

  int colbase = lane & 15;
  int rowo = r0 + kg * 4;
#pragma unroll
  for (int ct = 0; ct < 8; ++ct){
    int col = ct * 16 + colbase;
#pragma unroll
    for (int r = 0; r < 4; ++r){
      int rr = rowo + r;
      if (rr < nrows) hw[(long)rr * D + col] = f2bf(acc[ct][r]);
    }
  }
}

// ---------------- aggregate + BN partial stats ----------------
// Flattened segmented edge-walk: continuous unroll-8 gather stream over the
// wave's contiguous edge range (node-snapped -> no atomics). Node crossings
// are wave-uniform scalar events; next node's bound/self/selfrow prefetched
// one flush ahead so flushes never stall the gather stream.
__global__ __launch_bounds__(256)
void k_agg(const unsigned short* __restrict__ hw, const float* __restrict__ inv,
           const int* __restrict__ offs, const int* __restrict__ csrc,
           const float* __restrict__ cw, const float* __restrict__ bias,
           float* __restrict__ agg, float* __restrict__ stats, int n){
  int tid = threadIdx.x, lane = tid & 63, wv = tid >> 6;
  int gw = blockIdx.x * 4 + wv;
  int nwaves = gridDim.x * 4;
  int per = (n + nwaves - 1) / nwaves;
  int n0 = min(gw * per, n), n1 = min(n0 + per, n);
  int c0 = lane * 2;
  float b0 = bias[c0], b1 = bias[c0 + 1];
  float s0 = 0, s1 = 0, q0 = 0, q1 = 0;

  int nd = n0;
  int e = offs[nd];
  int eEnd = offs[n1];
  int bound = offs[min(nd + 1, n)];
  float selfc; { float t = inv[min(nd, n - 1)]; selfc = t * t; }
  unsigned selfrow = *(const unsigned*)(hw + (long)min(nd, n - 1) * D + c0);
  int bound_nx = offs[min(nd + 2, n)];
  float self_nx; { float t = inv[min(nd + 1, n - 1)]; self_nx = t * t; }
  unsigned selfrow_nx = *(const unsigned*)(hw + (long)min(nd + 1, n - 1) * D + c0);
  float acc0 = 0, acc1 = 0;

  while (nd < n1){
    float wP[8]; unsigned vP[8];
    int sP[8];
#pragma unroll
    for (int p = 0; p < 8; ++p){
      int idx = e + p;
      bool ok = idx < eEnd;
      int ic = ok ? idx : eEnd - 1;
      sP[p] = csrc[ic];
      wP[p] = ok ? cw[ic] : 0.f;
    }
#pragma unroll
    for (int p = 0; p < 8; ++p)
      vP[p] = *(const unsigned*)(hw + (long)sP[p] * D + c0);
#pragma unroll
    for (int p = 0; p < 8; ++p){
      while (nd < n1 && e + p == bound){
        float f0 = acc0 + bflo2f(selfrow) * selfc + b0;
        float f1 = acc1 + bfhi2f(selfrow) * selfc + b1;
        f32x2 rr; rr[0] = f0; rr[1] = f1;
        __builtin_nontemporal_store(rr, (f32x2*)(agg + (long)nd * D + c0));
        s0 += f0; s1 += f1; q0 += f0 * f0; q1 += f1 * f1;
        acc0 = 0; acc1 = 0;
        ++nd;
        bound = bound_nx; selfc = self_nx; selfrow = selfrow_nx;
        int pf = min(nd + 1, n - 1);
        bound_nx = offs[min(nd + 2, n)];
        { float t = inv[pf]; self_nx = t * t; }
        selfrow_nx = *(const unsigned*)(hw + (long)pf * D + c0);
      }
      acc0 += bflo2f(vP[p]) * wP[p];
      acc1 += bfhi2f(vP[p]) * wP[p];
    }
    e += 8;
  }

  __shared__ float red[4][64][4];
  red[wv][lane][0] = s0; red[wv][lane][1] = s1;
  red[wv][lane][2] = q0; red[wv][lane][3] = q1;
  __syncthreads();
  if (tid < 64){
    float t0 = 0, t1 = 0, t2 = 0, t3 = 0;
#pragma unroll
    for (int w = 0; w < 4; ++w){
      t0 += red[w][tid][0]; t1 += red[w][tid][1];
      t2 += red[w][tid][2]; t3 += red[w][tid][3];
    }
    atomicAdd(&stats[2 * tid],           t0);
    atomicAdd(&stats[2 * tid + 1],       t1);
    atomicAdd(&stats[128 + 2 * tid],     t2);
    atomicAdd(&stats[128 + 2 * tid + 1], t3);
  }
}

// ---------------- BN finalize ----------------
__global__ void k_bn(const float* __restrict__ stats, const float* __restrict__ gamma,
                     const float* __restrict__ beta, float* __restrict__ scale,
                     float* __restrict__ shift, float invn){
  int c = threadIdx.x;
  float mean = stats[c] * invn;
  float var = stats[128 + c] * invn - mean * mean;
  float isd = rsqrtf(var + 1e-5f);
  float sc = gamma[c] * isd;
  scale[c] = sc;
  shift[c] = beta[c] - mean * sc;
}

// ---------------- pool (fused BN+ReLU of last layer) ----------------
__global__ __launch_bounds__(256)
void k_pool(const float* __restrict__ agg, const float* __restrict__ scale,
            const float* __restrict__ shift, const int* __restrict__ batch,
            float* __restrict__ out, int n){
  int tid = threadIdx.x, lane = tid & 63, wv = tid >> 6;
  int gw = blockIdx.x * 4 + wv;
  int n0 = gw * 64;
  if (n0 >= n) return;
  int n1 = min(n0 + 64, n);
  int c0 = lane * 2;
  float sc0 = scale[c0], sc1 = scale[c0 + 1];
  float sh0 = shift[c0], sh1 = shift[c0 + 1];
  int g = batch[n0];
  float a0 = 0, a1 = 0;
  for (int nd = n0; nd < n1; ++nd){
    int gn = batch[nd];
    if (gn != g){
      atomicAdd(&out[(long)g * D + c0],     a0);
      atomicAdd(&out[(long)g * D + c0 + 1], a1);
      a0 = 0; a1 = 0; g = gn;
    }
    f32x2 v = *(const f32x2*)(agg + (long)nd * D + c0);
    a0 += fmaxf(0.f, v[0] * sc0 + sh0);
    a1 += fmaxf(0.f, v[1] * sc1 + sh1);
  }
  atomicAdd(&out[(long)g * D + c0],     a0);
  atomicAdd(&out[(long)g * D + c0 + 1], a1);
}

extern "C" void kernel_launch(void* const* d_in, const int* in_sizes, int n_in,
                              void* d_out, int out_size, void* d_ws, size_t ws_size,
                              hipStream_t stream){
  const float* x      = (const float*)d_in[0];
  const int*   ei     = (const int*)d_in[1];
  const int*   batch  = (const int*)d_in[2];
  const float* Ws     = (const float*)d_in[3];
  const float* bs     = (const float*)d_in[4];
  const float* gammas = (const float*)d_in[5];
  const float* betas  = (const float*)d_in[6];

  const int E_ = in_sizes[1] / 2;
  const int N_ = in_sizes[2];
  const int* src = ei;
  const int* dst = ei + E_;

  char* p = (char*)d_ws;
  auto alloc = [&](size_t bytes) -> void* {
    void* r = (void*)p;
    p += (bytes + 255) & ~(size_t)255;
    return r;
  };
  float*          bufA   = (float*)         alloc((size_t)N_ * D * 4);
  unsigned short* hw     = (unsigned short*)alloc((size_t)N_ * D * 2);
  int*            deg    = (int*)           alloc((size_t)N_ * 4);
  float*          inv    = (float*)         alloc((size_t)N_ * 4);
  int*            offs   = (int*)           alloc((size_t)(N_ + 1) * 4);
  int*            cursor = (int*)           alloc((size_t)N_ * 4);
  int*            csrc   = (int*)           alloc((size_t)E_ * 4);
  float*          cwt    = (float*)         alloc((size_t)E_ * 4);
  float*          stats  = (float*)         alloc(3 * 256 * 4);
  float*          scales = (float*)         alloc(3 * 128 * 4);
  float*          shifts = (float*)         alloc(3 * 128 * 4);
  int*            csum   = (int*)           alloc(256 * 4);

  hipMemsetAsync(deg,    0, (size_t)N_ * 4, stream);
  hipMemsetAsync(cursor, 0, (size_t)N_ * 4, stream);
  hipMemsetAsync(stats,  0, 3 * 256 * 4, stream);
  hipMemsetAsync(d_out,  0, (size_t)out_size * 4, stream);

  int nchunks = (N_ + CHUNK - 1) / CHUNK;
  k_deg       <<<(E_ + 255) / 256, 256, 0, stream>>>(dst, deg, E_);
  k_chunksum  <<<nchunks, 256, 0, stream>>>(deg, csum, N_);
  k_scanchunks<<<1, 256, 0, stream>>>(csum, nchunks);
  k_offsets   <<<nchunks, 256, 0, stream>>>(deg, csum, offs, inv, N_);
  k_csrfill   <<<(E_ + 255) / 256, 256, 0, stream>>>(src, dst, offs, cursor, inv, csrc, cwt, E_);

  int gemm_blocks = (N_ + 127) / 128;
  for (int l = 0; l < 3; ++l){
    const float* hin = (l == 0) ? x : bufA;
    const float* sc  = (l == 0) ? nullptr : scales + (l - 1) * 128;
    const float* sh  = (l == 0) ? nullptr : shifts + (l - 1) * 128;
    k_gemm<<<gemm_blocks, 512, 0, stream>>>(hin, Ws + (size_t)l * D * D, sc, sh,
                                            (l == 0) ? 0 : 1, hw, N_);
    k_agg<<<2048, 256, 0, stream>>>(hw, inv, offs, csrc, cwt, bs + (size_t)l * D,
                                    bufA, stats + (size_t)l * 256, N_);
    k_bn<<<1, 128, 0, stream>>>(stats + (size_t)l * 256, gammas + (size_t)l * D,
                                betas + (size_t)l * D, scales + (size_t)l * 128,
                                shifts + (size_t)l * 128, 1.0f / (float)N_);
  }
  k_pool<<<(N_ + 255) / 256, 256, 0, stream>>>(bufA, scales + 2 * 128, shifts + 2 * 128,
                                               batch, (float*)d_out, N_);
}

// Round 6
// 771.438 us; speedup vs baseline: 1.3773x; 1.0235x over previous
//
#include <hip/hip_runtime.h>

#define D 128
#define CHUNK 512

using short8 = __attribute__((ext_vector_type(8))) short;
using f32x4  = __attribute__((ext_vector_type(4))) float;
using f32x2  = __attribute__((ext_vector_type(2))) float;

__device__ __forceinline__ unsigned short f2bf(float f){
  unsigned u = __builtin_bit_cast(unsigned, f);
  u += 0x7fffu + ((u >> 16) & 1u);           // round-to-nearest-even
  return (unsigned short)(u >> 16);
}
__device__ __forceinline__ float bflo2f(unsigned v){
  return __builtin_bit_cast(float, v << 16);
}
__device__ __forceinline__ float bfhi2f(unsigned v){
  return __builtin_bit_cast(float, v & 0xffff0000u);
}
__device__ __forceinline__ float bfs2f(unsigned short v){
  return __builtin_bit_cast(float, ((unsigned)v) << 16);
}

// ---------------- degree ----------------
__global__ void k_deg(const int* __restrict__ dst, int* __restrict__ deg, int E){
  int e = blockIdx.x * 256 + threadIdx.x;
  if (e < E) atomicAdd(&deg[dst[e]], 1);
}

// ---------------- scan (3-stage) ----------------
__global__ void k_chunksum(const int* __restrict__ deg, int* __restrict__ csum, int n){
  __shared__ int s[256];
  int tid = threadIdx.x;
  int n0 = blockIdx.x * CHUNK + tid * 2;
  int v = 0;
  if (n0     < n) v += deg[n0];
  if (n0 + 1 < n) v += deg[n0 + 1];
  s[tid] = v; __syncthreads();
  for (int off = 128; off > 0; off >>= 1){
    if (tid < off) s[tid] += s[tid + off];
    __syncthreads();
  }
  if (tid == 0) csum[blockIdx.x] = s[0];
}

__global__ void k_scanchunks(int* __restrict__ csum, int nchunks){
  __shared__ int s[256];
  int tid = threadIdx.x;
  int v = (tid < nchunks) ? csum[tid] : 0;
  s[tid] = v; __syncthreads();
  for (int off = 1; off < 256; off <<= 1){
    int t = (tid >= off) ? s[tid - off] : 0;
    __syncthreads();
    s[tid] += t;
    __syncthreads();
  }
  if (tid < nchunks) csum[tid] = s[tid] - v;   // exclusive
}

__global__ void k_offsets(const int* __restrict__ deg, const int* __restrict__ csum,
                          int* __restrict__ offs, float* __restrict__ inv, int n){
  __shared__ int s[256];
  int tid = threadIdx.x;
  int n0 = blockIdx.x * CHUNK + tid * 2;
  int d0 = (n0     < n) ? deg[n0]     : 0;
  int d1 = (n0 + 1 < n) ? deg[n0 + 1] : 0;
  int pair = d0 + d1;
  s[tid] = pair; __syncthreads();
  for (int off = 1; off < 256; off <<= 1){
    int t = (tid >= off) ? s[tid - off] : 0;
    __syncthreads();
    s[tid] += t;
    __syncthreads();
  }
  int excl = s[tid] - pair + csum[blockIdx.x];
  if (n0     <= n) offs[n0]     = excl;
  if (n0 + 1 <= n) offs[n0 + 1] = excl + d0;
  if (n0     < n) inv[n0]     = rsqrtf((float)(d0 + 1));
  if (n0 + 1 < n) inv[n0 + 1] = rsqrtf((float)(d1 + 1));
}

// ---------------- CSR fill (index only — weight folded into hw rows) ------
__global__ void k_csrfill(const int* __restrict__ src, const int* __restrict__ dst,
                          const int* __restrict__ offs, int* __restrict__ cursor,
                          int* __restrict__ csrc, int E){
  int e = blockIdx.x * 256 + threadIdx.x;
  if (e >= E) return;
  int s = src[e], d = dst[e];
  int pos = offs[d] + atomicAdd(&cursor[d], 1);
  csrc[pos] = s;
}

// ---------------- GEMM: hw(bf16) = act(hin) @ W, rows pre-scaled by inv ----
// act = identity (do_norm=0, f32 input) or relu(x*scale+shift) (bf16 input)
#define WSTRIDE 136
__global__ __launch_bounds__(512)
void k_gemm(const float* __restrict__ hf, const unsigned short* __restrict__ hb,
            const float* __restrict__ W, const float* __restrict__ inv,
            const float* __restrict__ scale, const float* __restrict__ shift,
            int do_norm, unsigned short* __restrict__ hw, int nrows){
  __shared__ unsigned short Wt[128 * WSTRIDE];  // transposed, padded
  int tid = threadIdx.x;
  for (int i = tid; i < 128 * 128; i += 512){
    int k = i >> 7, c = i & 127;
    Wt[c * WSTRIDE + k] = f2bf(W[i]);
  }
  __syncthreads();

  int wave = tid >> 6, lane = tid & 63;
  int r0 = blockIdx.x * 128 + wave * 16;
  int row = r0 + (lane & 15);
  int kg = lane >> 4;
  int rowc = row < nrows ? row : nrows - 1;

  short8 a[4];
  if (do_norm){
    const unsigned short* hrow = hb + (long)rowc * D;
#pragma unroll
    for (int kt = 0; kt < 4; ++kt){
      int k0 = kt * 32 + kg * 8;
      short8 raw = *(const short8*)(hrow + k0);
      short8 t;
#pragma unroll
      for (int j = 0; j < 8; ++j){
        float v = bfs2f((unsigned short)raw[j]);
        v = fmaxf(0.f, v * scale[k0 + j] + shift[k0 + j]);
        t[j] = (short)f2bf(v);
      }
      a[kt] = t;
    }
  } else {
    const float* hrow = hf + (long)rowc * D;
#pragma unroll
    for (int kt = 0; kt < 4; ++kt){
      int k0 = kt * 32 + kg * 8;
      f32x4 v0 = *(const f32x4*)(hrow + k0);
      f32x4 v1 = *(const f32x4*)(hrow + k0 + 4);
      short8 t;
      t[0] = (short)f2bf(v0[0]); t[1] = (short)f2bf(v0[1]);
      t[2] = (short)f2bf(v0[2]); t[3] = (short)f2bf(v0[3]);
      t[4] = (short)f2bf(v1[0]); t[5] = (short)f2bf(v1[1]);
      t[6] = (short)f2bf(v1[2]); t[7] = (short)f2bf(v1[3]);
      a[kt] = t;
    }
  }

  f32x4 acc[8] = {};
#pragma unroll
  for (int ct = 0; ct < 8; ++ct){
    int col = ct * 16 + (lane & 15);
    const unsigned short* bp = &Wt[col * WSTRIDE + kg * 8];
#pragma unroll
    for (int kt = 0; kt < 4; ++kt){
      short8 b = *(const short8*)(bp + kt * 32);
      acc[ct] = __builtin_amdgcn_mfma_f32_16x16x32_bf16(a[kt], b, acc[ct], 0, 0, 0);
    }
  }

  int colbase = lane & 15;
  int rowo = r0 + kg * 4;
  float ivr[4];
#pragma unroll
  for (int r = 0; r < 4; ++r) ivr[r] = inv[min(rowo + r, nrows - 1)];
#pragma unroll
  for (int ct = 0; ct < 8; ++ct){
    int col = ct * 16 + colbase;
#pragma unroll
    for (int r = 0; r < 4; ++r){
      int rr = rowo + r;
      if (rr < nrows) hw[(long)rr * D + col] = f2bf(acc[ct][r] * ivr[r]);
    }
  }
}

// ---------------- aggregate + BN partial stats ----------------
// R2-exact structure (uniform scalar csrc loads, full-wave 256B row gathers,
// 4 independent accumulators + predicated tail). Rows pre-scaled by inv[src]
// -> inner loop is pure gather+add; flush multiplies once by inv[dst].
// agg stored bf16-packed (halves write traffic).
__global__ __launch_bounds__(256)
void k_agg(const unsigned short* __restrict__ hw, const float* __restrict__ inv,
           const int* __restrict__ offs, const int* __restrict__ csrc,
           const float* __restrict__ bias,
           unsigned* __restrict__ agg, float* __restrict__ stats, int n){
  int tid = threadIdx.x, lane = tid & 63, wv = tid >> 6;
  int gw = blockIdx.x * 4 + wv;
  int nwaves = gridDim.x * 4;
  int per = (n + nwaves - 1) / nwaves;
  int n0 = min(gw * per, n), n1 = min(n0 + per, n);
  int c0 = lane * 2;
  float b0 = bias[c0], b1 = bias[c0 + 1];
  float s0 = 0, s1 = 0, q0 = 0, q1 = 0;

  for (int nd = n0; nd < n1; ++nd){
    float ivd = inv[nd];
    unsigned selfv = *(const unsigned*)(hw + (long)nd * D + c0);
    float x0[4] = {0,0,0,0};
    float x1[4] = {0,0,0,0};
    int e = offs[nd], ee = offs[nd + 1];
    for (; e + 4 <= ee; e += 4){
#pragma unroll
      for (int p = 0; p < 4; ++p){
        int s = csrc[e + p];
        unsigned vv = *(const unsigned*)(hw + (long)s * D + c0);
        x0[p] += bflo2f(vv);
        x1[p] += bfhi2f(vv);
      }
    }
    if (e < ee){
      int last = ee - 1;
#pragma unroll
      for (int p = 0; p < 4; ++p){
        int idx = e + p;
        bool ok = idx < ee;
        int s = csrc[ok ? idx : last];
        float f = ok ? 1.f : 0.f;
        unsigned vv = *(const unsigned*)(hw + (long)s * D + c0);
        x0[p] += bflo2f(vv) * f;
        x1[p] += bfhi2f(vv) * f;
      }
    }
    float a0 = ((x0[0] + x0[1]) + (x0[2] + x0[3]) + bflo2f(selfv)) * ivd + b0;
    float a1 = ((x1[0] + x1[1]) + (x1[2] + x1[3]) + bfhi2f(selfv)) * ivd + b1;
    unsigned pk = ((unsigned)f2bf(a1) << 16) | (unsigned)f2bf(a0);
    __builtin_nontemporal_store(pk, agg + (long)nd * (D / 2) + lane);
    s0 += a0; s1 += a1; q0 += a0 * a0; q1 += a1 * a1;
  }

  __shared__ float red[4][64][4];
  red[wv][lane][0] = s0; red[wv][lane][1] = s1;
  red[wv][lane][2] = q0; red[wv][lane][3] = q1;
  __syncthreads();
  if (tid < 64){
    float t0 = 0, t1 = 0, t2 = 0, t3 = 0;
#pragma unroll
    for (int w = 0; w < 4; ++w){
      t0 += red[w][tid][0]; t1 += red[w][tid][1];
      t2 += red[w][tid][2]; t3 += red[w][tid][3];
    }
    atomicAdd(&stats[2 * tid],           t0);
    atomicAdd(&stats[2 * tid + 1],       t1);
    atomicAdd(&stats[128 + 2 * tid],     t2);
    atomicAdd(&stats[128 + 2 * tid + 1], t3);
  }
}

// ---------------- BN finalize ----------------
__global__ void k_bn(const float* __restrict__ stats, const float* __restrict__ gamma,
                     const float* __restrict__ beta, float* __restrict__ scale,
                     float* __restrict__ shift, float invn){
  int c = threadIdx.x;
  float mean = stats[c] * invn;
  float var = stats[128 + c] * invn - mean * mean;
  float isd = rsqrtf(var + 1e-5f);
  float sc = gamma[c] * isd;
  scale[c] = sc;
  shift[c] = beta[c] - mean * sc;
}

// ---------------- pool (fused BN+ReLU of last layer, bf16 agg input) -------
__global__ __launch_bounds__(256)
void k_pool(const unsigned* __restrict__ agg, const float* __restrict__ scale,
            const float* __restrict__ shift, const int* __restrict__ batch,
            float* __restrict__ out, int n){
  int tid = threadIdx.x, lane = tid & 63, wv = tid >> 6;
  int gw = blockIdx.x * 4 + wv;
  int n0 = gw * 64;
  if (n0 >= n) return;
  int n1 = min(n0 + 64, n);
  int c0 = lane * 2;
  float sc0 = scale[c0], sc1 = scale[c0 + 1];
  float sh0 = shift[c0], sh1 = shift[c0 + 1];
  int g = batch[n0];
  float a0 = 0, a1 = 0;
  for (int nd = n0; nd < n1; ++nd){
    int gn = batch[nd];
    if (gn != g){
      atomicAdd(&out[(long)g * D + c0],     a0);
      atomicAdd(&out[(long)g * D + c0 + 1], a1);
      a0 = 0; a1 = 0; g = gn;
    }
    unsigned v = agg[(long)nd * (D / 2) + lane];
    a0 += fmaxf(0.f, bflo2f(v) * sc0 + sh0);
    a1 += fmaxf(0.f, bfhi2f(v) * sc1 + sh1);
  }
  atomicAdd(&out[(long)g * D + c0],     a0);
  atomicAdd(&out[(long)g * D + c0 + 1], a1);
}

extern "C" void kernel_launch(void* const* d_in, const int* in_sizes, int n_in,
                              void* d_out, int out_size, void* d_ws, size_t ws_size,
                              hipStream_t stream){
  const float* x      = (const float*)d_in[0];
  const int*   ei     = (const int*)d_in[1];
  const int*   batch  = (const int*)d_in[2];
  const float* Ws     = (const float*)d_in[3];
  const float* bs     = (const float*)d_in[4];
  const float* gammas = (const float*)d_in[5];
  const float* betas  = (const float*)d_in[6];

  const int E_ = in_sizes[1] / 2;
  const int N_ = in_sizes[2];
  const int* src = ei;
  const int* dst = ei + E_;

  char* p = (char*)d_ws;
  auto alloc = [&](size_t bytes) -> void* {
    void* r = (void*)p;
    p += (bytes + 255) & ~(size_t)255;
    return r;
  };
  unsigned*       bufA   = (unsigned*)      alloc((size_t)N_ * D * 2);   // bf16 agg
  unsigned short* hw     = (unsigned short*)alloc((size_t)N_ * D * 2);
  int*            deg    = (int*)           alloc((size_t)N_ * 4);
  float*          inv    = (float*)         alloc((size_t)N_ * 4);
  int*            offs   = (int*)           alloc((size_t)(N_ + 1) * 4);
  int*            cursor = (int*)           alloc((size_t)N_ * 4);
  int*            csrc   = (int*)           alloc((size_t)E_ * 4);
  float*          stats  = (float*)         alloc(3 * 256 * 4);
  float*          scales = (float*)         alloc(3 * 128 * 4);
  float*          shifts = (float*)         alloc(3 * 128 * 4);
  int*            csum   = (int*)           alloc(256 * 4);

  hipMemsetAsync(deg,    0, (size_t)N_ * 4, stream);
  hipMemsetAsync(cursor, 0, (size_t)N_ * 4, stream);
  hipMemsetAsync(stats,  0, 3 * 256 * 4, stream);
  hipMemsetAsync(d_out,  0, (size_t)out_size * 4, stream);

  int nchunks = (N_ + CHUNK - 1) / CHUNK;
  k_deg       <<<(E_ + 255) / 256, 256, 0, stream>>>(dst, deg, E_);
  k_chunksum  <<<nchunks, 256, 0, stream>>>(deg, csum, N_);
  k_scanchunks<<<1, 256, 0, stream>>>(csum, nchunks);
  k_offsets   <<<nchunks, 256, 0, stream>>>(deg, csum, offs, inv, N_);
  k_csrfill   <<<(E_ + 255) / 256, 256, 0, stream>>>(src, dst, offs, cursor, csrc, E_);

  int gemm_blocks = (N_ + 127) / 128;
  for (int l = 0; l < 3; ++l){
    const float* sc = (l == 0) ? nullptr : scales + (l - 1) * 128;
    const float* sh = (l == 0) ? nullptr : shifts + (l - 1) * 128;
    k_gemm<<<gemm_blocks, 512, 0, stream>>>(x, (const unsigned short*)bufA,
                                            Ws + (size_t)l * D * D, inv, sc, sh,
                                            (l == 0) ? 0 : 1, hw, N_);
    k_agg<<<2048, 256, 0, stream>>>(hw, inv, offs, csrc, bs + (size_t)l * D,
                                    bufA, stats + (size_t)l * 256, N_);
    k_bn<<<1, 128, 0, stream>>>(stats + (size_t)l * 256, gammas + (size_t)l * D,
                                betas + (size_t)l * D, scales + (size_t)l * 128,
                                shifts + (size_t)l * 128, 1.0f / (float)N_);
  }
  k_pool<<<(N_ + 255) / 256, 256, 0, stream>>>(bufA, scales + 2 * 128, shifts + 2 * 128,
                                               batch, (float*)d_out, N_);
}

// Round 7
// 765.239 us; speedup vs baseline: 1.3885x; 1.0081x over previous
//
#include <hip/hip_runtime.h>

#define D 128
#define CHUNK 512
#define NSLICE 8
#define SLW 16            // cols per slice

using short8 = __attribute__((ext_vector_type(8))) short;
using f32x4  = __attribute__((ext_vector_type(4))) float;
using f32x2  = __attribute__((ext_vector_type(2))) float;

__device__ __forceinline__ unsigned short f2bf(float f){
  unsigned u = __builtin_bit_cast(unsigned, f);
  u += 0x7fffu + ((u >> 16) & 1u);           // round-to-nearest-even
  return (unsigned short)(u >> 16);
}
__device__ __forceinline__ float bflo2f(unsigned v){
  return __builtin_bit_cast(float, v << 16);
}
__device__ __forceinline__ float bfhi2f(unsigned v){
  return __builtin_bit_cast(float, v & 0xffff0000u);
}
__device__ __forceinline__ float bfs2f(unsigned short v){
  return __builtin_bit_cast(float, ((unsigned)v) << 16);
}

// ---------------- degree ----------------
__global__ void k_deg(const int* __restrict__ dst, int* __restrict__ deg, int E){
  int e = blockIdx.x * 256 + threadIdx.x;
  if (e < E) atomicAdd(&deg[dst[e]], 1);
}

// ---------------- scan (3-stage) ----------------
__global__ void k_chunksum(const int* __restrict__ deg, int* __restrict__ csum, int n){
  __shared__ int s[256];
  int tid = threadIdx.x;
  int n0 = blockIdx.x * CHUNK + tid * 2;
  int v = 0;
  if (n0     < n) v += deg[n0];
  if (n0 + 1 < n) v += deg[n0 + 1];
  s[tid] = v; __syncthreads();
  for (int off = 128; off > 0; off >>= 1){
    if (tid < off) s[tid] += s[tid + off];
    __syncthreads();
  }
  if (tid == 0) csum[blockIdx.x] = s[0];
}

__global__ void k_scanchunks(int* __restrict__ csum, int nchunks){
  __shared__ int s[256];
  int tid = threadIdx.x;
  int v = (tid < nchunks) ? csum[tid] : 0;
  s[tid] = v; __syncthreads();
  for (int off = 1; off < 256; off <<= 1){
    int t = (tid >= off) ? s[tid - off] : 0;
    __syncthreads();
    s[tid] += t;
    __syncthreads();
  }
  if (tid < nchunks) csum[tid] = s[tid] - v;   // exclusive
}

__global__ void k_offsets(const int* __restrict__ deg, const int* __restrict__ csum,
                          int* __restrict__ offs, float* __restrict__ inv, int n){
  __shared__ int s[256];
  int tid = threadIdx.x;
  int n0 = blockIdx.x * CHUNK + tid * 2;
  int d0 = (n0     < n) ? deg[n0]     : 0;
  int d1 = (n0 + 1 < n) ? deg[n0 + 1] : 0;
  int pair = d0 + d1;
  s[tid] = pair; __syncthreads();
  for (int off = 1; off < 256; off <<= 1){
    int t = (tid >= off) ? s[tid - off] : 0;
    __syncthreads();
    s[tid] += t;
    __syncthreads();
  }
  int excl = s[tid] - pair + csum[blockIdx.x];
  if (n0     <= n) offs[n0]     = excl;
  if (n0 + 1 <= n) offs[n0 + 1] = excl + d0;
  if (n0     < n) inv[n0]     = rsqrtf((float)(d0 + 1));
  if (n0 + 1 < n) inv[n0 + 1] = rsqrtf((float)(d1 + 1));
}

// ---------------- CSR fill (index only — weight folded into hw rows) ------
__global__ void k_csrfill(const int* __restrict__ src, const int* __restrict__ dst,
                          const int* __restrict__ offs, int* __restrict__ cursor,
                          int* __restrict__ csrc, int E){
  int e = blockIdx.x * 256 + threadIdx.x;
  if (e >= E) return;
  int s = src[e], d = dst[e];
  int pos = offs[d] + atomicAdd(&cursor[d], 1);
  csrc[pos] = s;
}

// ---------------- GEMM: hwS(bf16, slice-major) = act(hin) @ W, rows × inv --
// hwS layout: [slice][N][16] ushorts. agg input (do_norm) also slice-major.
#define WSTRIDE 136
__global__ __launch_bounds__(512)
void k_gemm(const float* __restrict__ hf, const unsigned short* __restrict__ hb,
            const float* __restrict__ W, const float* __restrict__ inv,
            const float* __restrict__ scale, const float* __restrict__ shift,
            int do_norm, unsigned short* __restrict__ hwS, int nrows){
  __shared__ unsigned short Wt[128 * WSTRIDE];  // transposed, padded
  int tid = threadIdx.x;
  for (int i = tid; i < 128 * 128; i += 512){
    int k = i >> 7, c = i & 127;
    Wt[c * WSTRIDE + k] = f2bf(W[i]);
  }
  __syncthreads();

  int wave = tid >> 6, lane = tid & 63;
  int r0 = blockIdx.x * 128 + wave * 16;
  int row = r0 + (lane & 15);
  int kg = lane >> 4;
  int rowc = row < nrows ? row : nrows - 1;

  short8 a[4];
  if (do_norm){
#pragma unroll
    for (int kt = 0; kt < 4; ++kt){
      int k0 = kt * 32 + kg * 8;                 // 8 cols within one slice
      int sl = k0 >> 4, o = k0 & 15;
      short8 raw = *(const short8*)(hb + ((long)sl * nrows + rowc) * SLW + o);
      short8 t;
#pragma unroll
      for (int j = 0; j < 8; ++j){
        float v = bfs2f((unsigned short)raw[j]);
        v = fmaxf(0.f, v * scale[k0 + j] + shift[k0 + j]);
        t[j] = (short)f2bf(v);
      }
      a[kt] = t;
    }
  } else {
    const float* hrow = hf + (long)rowc * D;
#pragma unroll
    for (int kt = 0; kt < 4; ++kt){
      int k0 = kt * 32 + kg * 8;
      f32x4 v0 = *(const f32x4*)(hrow + k0);
      f32x4 v1 = *(const f32x4*)(hrow + k0 + 4);
      short8 t;
      t[0] = (short)f2bf(v0[0]); t[1] = (short)f2bf(v0[1]);
      t[2] = (short)f2bf(v0[2]); t[3] = (short)f2bf(v0[3]);
      t[4] = (short)f2bf(v1[0]); t[5] = (short)f2bf(v1[1]);
      t[6] = (short)f2bf(v1[2]); t[7] = (short)f2bf(v1[3]);
      a[kt] = t;
    }
  }

  f32x4 acc[8] = {};
#pragma unroll
  for (int ct = 0; ct < 8; ++ct){
    int col = ct * 16 + (lane & 15);
    const unsigned short* bp = &Wt[col * WSTRIDE + kg * 8];
#pragma unroll
    for (int kt = 0; kt < 4; ++kt){
      short8 b = *(const short8*)(bp + kt * 32);
      acc[ct] = __builtin_amdgcn_mfma_f32_16x16x32_bf16(a[kt], b, acc[ct], 0, 0, 0);
    }
  }

  int colbase = lane & 15;
  int rowo = r0 + kg * 4;
  float ivr[4];
#pragma unroll
  for (int r = 0; r < 4; ++r) ivr[r] = inv[min(rowo + r, nrows - 1)];
#pragma unroll
  for (int ct = 0; ct < 8; ++ct){        // slice = ct (cols ct*16..ct*16+15)
#pragma unroll
    for (int r = 0; r < 4; ++r){
      int rr = rowo + r;
      if (rr < nrows)
        hwS[((long)ct * nrows + rr) * SLW + colbase] = f2bf(acc[ct][r] * ivr[r]);
    }
  }
}

// ---------------- aggregate + BN partial stats (column-sliced) -------------
// block = grp*8 + g: slice g rides blockIdx%8 -> one XCD (round-robin
// dispatch), so each XCD gathers only its 3.2 MB hw slice (L2-resident).
// lane = edge-slot(eg,8) x colpair(cp,8); 8 edges per gather instr, unroll x2.
__global__ __launch_bounds__(256)
void k_agg(const unsigned short* __restrict__ hwS, const float* __restrict__ inv,
           const int* __restrict__ offs, const int* __restrict__ csrc,
           const float* __restrict__ bias,
           unsigned* __restrict__ aggS, float* __restrict__ stats, int n,
           int ngroups){
  int g   = blockIdx.x & 7;
  int grp = blockIdx.x >> 3;
  int tid = threadIdx.x, lane = tid & 63, wv = tid >> 6;
  int eg = lane >> 3;          // edge slot 0..7
  int cp = lane & 7;           // col pair 0..7  (cols g*16+cp*2, +1)
  int nwaves = ngroups * 4;
  int gw = grp * 4 + wv;
  int per = (n + nwaves - 1) / nwaves;
  int n0 = min(gw * per, n), n1 = min(n0 + per, n);

  const unsigned* hw32 = (const unsigned*)hwS;     // (g*n + row)*8 + cp
  long sbase = (long)g * n * 8;

  float b0 = bias[g * 16 + cp * 2], b1 = bias[g * 16 + cp * 2 + 1];
  float s0 = 0, s1 = 0, q0 = 0, q1 = 0;

  for (int nd = n0; nd < n1; ++nd){
    float ivd = inv[nd];
    unsigned selfv = hw32[sbase + (long)nd * 8 + cp];
    float a0 = 0, a1 = 0;
    int e = offs[nd], ee = offs[nd + 1];
    for (; e + 16 <= ee; e += 16){
      int sA = csrc[e + eg];
      int sB = csrc[e + 8 + eg];
      unsigned vA = hw32[sbase + (long)sA * 8 + cp];
      unsigned vB = hw32[sbase + (long)sB * 8 + cp];
      a0 += bflo2f(vA) + bflo2f(vB);
      a1 += bfhi2f(vA) + bfhi2f(vB);
    }
    if (e < ee){
      int last = ee - 1;
      int iA = e + eg, iB = e + 8 + eg;
      float fA = (iA < ee) ? 1.f : 0.f;
      float fB = (iB < ee) ? 1.f : 0.f;
      int sA = csrc[iA < ee ? iA : last];
      int sB = csrc[iB < ee ? iB : last];
      unsigned vA = hw32[sbase + (long)sA * 8 + cp];
      unsigned vB = hw32[sbase + (long)sB * 8 + cp];
      a0 += bflo2f(vA) * fA + bflo2f(vB) * fB;
      a1 += bfhi2f(vA) * fA + bfhi2f(vB) * fB;
    }
    // reduce across the 8 edge slots (lanes differing in bits 3..5)
    a0 += __shfl_xor(a0, 8, 64);  a1 += __shfl_xor(a1, 8, 64);
    a0 += __shfl_xor(a0, 16, 64); a1 += __shfl_xor(a1, 16, 64);
    a0 += __shfl_xor(a0, 32, 64); a1 += __shfl_xor(a1, 32, 64);
    a0 = (a0 + bflo2f(selfv)) * ivd + b0;
    a1 = (a1 + bfhi2f(selfv)) * ivd + b1;
    if (eg == 0){
      unsigned pk = ((unsigned)f2bf(a1) << 16) | (unsigned)f2bf(a0);
      __builtin_nontemporal_store(pk, aggS + sbase + (long)nd * 8 + cp);
      s0 += a0; s1 += a1; q0 += a0 * a0; q1 += a1 * a1;
    }
  }

  __shared__ float red[4][8][4];
  if (eg == 0){
    red[wv][cp][0] = s0; red[wv][cp][1] = s1;
    red[wv][cp][2] = q0; red[wv][cp][3] = q1;
  }
  __syncthreads();
  if (tid < 8){
    float t0 = 0, t1 = 0, t2 = 0, t3 = 0;
#pragma unroll
    for (int w = 0; w < 4; ++w){
      t0 += red[w][tid][0]; t1 += red[w][tid][1];
      t2 += red[w][tid][2]; t3 += red[w][tid][3];
    }
    int c = g * 16 + tid * 2;
    atomicAdd(&stats[c],           t0);
    atomicAdd(&stats[c + 1],       t1);
    atomicAdd(&stats[128 + c],     t2);
    atomicAdd(&stats[128 + c + 1], t3);
  }
}

// ---------------- BN finalize ----------------
__global__ void k_bn(const float* __restrict__ stats, const float* __restrict__ gamma,
                     const float* __restrict__ beta, float* __restrict__ scale,
                     float* __restrict__ shift, float invn){
  int c = threadIdx.x;
  float mean = stats[c] * invn;
  float var = stats[128 + c] * invn - mean * mean;
  float isd = rsqrtf(var + 1e-5f);
  float sc = gamma[c] * isd;
  scale[c] = sc;
  shift[c] = beta[c] - mean * sc;
}

// ---------------- pool (fused BN+ReLU of last layer, sliced bf16 agg) ------
__global__ __launch_bounds__(256)
void k_pool(const unsigned* __restrict__ aggS, const float* __restrict__ scale,
            const float* __restrict__ shift, const int* __restrict__ batch,
            float* __restrict__ out, int n){
  int tid = threadIdx.x, lane = tid & 63, wv = tid >> 6;
  int gw = blockIdx.x * 4 + wv;
  int n0 = gw * 64;
  if (n0 >= n) return;
  int n1 = min(n0 + 64, n);
  int c0 = lane * 2;
  int sl = lane >> 3, cp = lane & 7;
  long sbase = (long)sl * n * 8;
  float sc0 = scale[c0], sc1 = scale[c0 + 1];
  float sh0 = shift[c0], sh1 = shift[c0 + 1];
  int g = batch[n0];
  float a0 = 0, a1 = 0;
  for (int nd = n0; nd < n1; ++nd){
    int gn = batch[nd];
    if (gn != g){
      atomicAdd(&out[(long)g * D + c0],     a0);
      atomicAdd(&out[(long)g * D + c0 + 1], a1);
      a0 = 0; a1 = 0; g = gn;
    }
    unsigned v = aggS[sbase + (long)nd * 8 + cp];
    a0 += fmaxf(0.f, bflo2f(v) * sc0 + sh0);
    a1 += fmaxf(0.f, bfhi2f(v) * sc1 + sh1);
  }
  atomicAdd(&out[(long)g * D + c0],     a0);
  atomicAdd(&out[(long)g * D + c0 + 1], a1);
}

extern "C" void kernel_launch(void* const* d_in, const int* in_sizes, int n_in,
                              void* d_out, int out_size, void* d_ws, size_t ws_size,
                              hipStream_t stream){
  const float* x      = (const float*)d_in[0];
  const int*   ei     = (const int*)d_in[1];
  const int*   batch  = (const int*)d_in[2];
  const float* Ws     = (const float*)d_in[3];
  const float* bs     = (const float*)d_in[4];
  const float* gammas = (const float*)d_in[5];
  const float* betas  = (const float*)d_in[6];

  const int E_ = in_sizes[1] / 2;
  const int N_ = in_sizes[2];
  const int* src = ei;
  const int* dst = ei + E_;

  char* p = (char*)d_ws;
  auto alloc = [&](size_t bytes) -> void* {
    void* r = (void*)p;
    p += (bytes + 255) & ~(size_t)255;
    return r;
  };
  unsigned*       bufA   = (unsigned*)      alloc((size_t)N_ * D * 2);   // bf16 agg, sliced
  unsigned short* hwS    = (unsigned short*)alloc((size_t)N_ * D * 2);   // bf16 hw, sliced
  int*            deg    = (int*)           alloc((size_t)N_ * 4);
  float*          inv    = (float*)         alloc((size_t)N_ * 4);
  int*            offs   = (int*)           alloc((size_t)(N_ + 1) * 4);
  int*            cursor = (int*)           alloc((size_t)N_ * 4);
  int*            csrc   = (int*)           alloc((size_t)E_ * 4);
  float*          stats  = (float*)         alloc(3 * 256 * 4);
  float*          scales = (float*)         alloc(3 * 128 * 4);
  float*          shifts = (float*)         alloc(3 * 128 * 4);
  int*            csum   = (int*)           alloc(256 * 4);

  hipMemsetAsync(deg,    0, (size_t)N_ * 4, stream);
  hipMemsetAsync(cursor, 0, (size_t)N_ * 4, stream);
  hipMemsetAsync(stats,  0, 3 * 256 * 4, stream);
  hipMemsetAsync(d_out,  0, (size_t)out_size * 4, stream);

  int nchunks = (N_ + CHUNK - 1) / CHUNK;
  k_deg       <<<(E_ + 255) / 256, 256, 0, stream>>>(dst, deg, E_);
  k_chunksum  <<<nchunks, 256, 0, stream>>>(deg, csum, N_);
  k_scanchunks<<<1, 256, 0, stream>>>(csum, nchunks);
  k_offsets   <<<nchunks, 256, 0, stream>>>(deg, csum, offs, inv, N_);
  k_csrfill   <<<(E_ + 255) / 256, 256, 0, stream>>>(src, dst, offs, cursor, csrc, E_);

  int gemm_blocks = (N_ + 127) / 128;
  int ngroups = 256;                       // k_agg grid = ngroups*8 blocks
  for (int l = 0; l < 3; ++l){
    const float* sc = (l == 0) ? nullptr : scales + (l - 1) * 128;
    const float* sh = (l == 0) ? nullptr : shifts + (l - 1) * 128;
    k_gemm<<<gemm_blocks, 512, 0, stream>>>(x, (const unsigned short*)bufA,
                                            Ws + (size_t)l * D * D, inv, sc, sh,
                                            (l == 0) ? 0 : 1, hwS, N_);
    k_agg<<<ngroups * 8, 256, 0, stream>>>(hwS, inv, offs, csrc, bs + (size_t)l * D,
                                           bufA, stats + (size_t)l * 256, N_, ngroups);
    k_bn<<<1, 128, 0, stream>>>(stats + (size_t)l * 256, gammas + (size_t)l * D,
                                betas + (size_t)l * D, scales + (size_t)l * 128,
                                shifts + (size_t)l * 128, 1.0f / (float)N_);
  }
  k_pool<<<(N_ + 255) / 256, 256, 0, stream>>>(bufA, scales + 2 * 128, shifts + 2 * 128,
                                               batch, (float*)d_out, N_);
}